// Round 1
// baseline (125.776 us; speedup 1.0000x reference)
//
#include <hip/hip_runtime.h>
#include <math.h>

// Problem: B=8, T=8192, D=128, E=8, I=16.  BT = 65536 tokens.
// Outputs concatenated f32: out0 [BT,128] | out1 [BT,8] | out2 [BT,8,128]
#define O1_OFF 8388608
#define O2_OFF 8912896

typedef __attribute__((ext_vector_type(8))) short short8;
typedef __attribute__((ext_vector_type(4))) float f32x4;

static __device__ __forceinline__ unsigned short f2bf(float f) {
    unsigned u = __builtin_bit_cast(unsigned, f);
    u = (u + 0x7fffu + ((u >> 16) & 1u)) >> 16;   // RNE
    return (unsigned short)u;
}

// swizzled byte offset inside a [rows][16 x 16B-chunks] LDS region (256B rows)
static __device__ __forceinline__ int swz(int row, int chunk) {
    return row * 256 + ((chunk ^ (row & 7)) << 4);
}

// LDS-only barrier: does NOT drain vmcnt -> global stores stay in flight.
static __device__ __forceinline__ void bar_lds() {
    asm volatile("s_waitcnt lgkmcnt(0)" ::: "memory");
    __builtin_amdgcn_s_barrier();
    asm volatile("" ::: "memory");
}

__global__ __launch_bounds__(256, 3) void moe_fused(
    const float* __restrict__ x, const float* __restrict__ ln_g,
    const float* __restrict__ ln_b, const float* __restrict__ gate_w,
    const float* __restrict__ gate_b, const float* __restrict__ w1,
    const float* __restrict__ w2, float* __restrict__ out)
{
    // 50 KB: 3 blocks/CU
    __shared__ __align__(16) char smem[51200];
    char* pXY = smem;                      // 16KB: xn (bf16) -> y (bf16)
    char* pW  = smem + 16384;              // 32KB: w1t -> w2t -> x (f32)
    float* pRW = (float*)(smem + 49152);   // 2KB: routing weights [64][8] f32

    const int t = threadIdx.x;
    const int l = t & 63;
    const int w = t >> 6;
    const int tok0 = blockIdx.x * 64;

    const int colq = (t & 31) * 4;   // P0-layout columns
    const int rsub = t >> 5;         // P0-layout row sub-index

    const int rb = w * 16;           // wave's 16 token rows
    const int tl = l & 15;           // lane's token (D-layout col after swap)
    const int ak = l >> 4;           // MFMA k-subgroup / D-layout row group

    //---------------- P0: global loads + staging ----------------
    float4 xv[8];                    // x tile, held in regs to the end
    {
        const float* xb = x + (size_t)tok0 * 128;
        #pragma unroll
        for (int s = 0; s < 8; ++s)
            xv[s] = *(const float4*)(xb + s * 1024 + t * 4);
    }
    float4 g4 = *(const float4*)(ln_g + colq);
    float4 b4 = *(const float4*)(ln_b + colq);

    // w2 staged in registers (bf16-packed) until w1t region is free (bar2)
    const int e2 = t >> 5;
    unsigned pk[4][8];
    {
        #pragma unroll
        for (int cc = 0; cc < 4; ++cc)
            #pragma unroll
            for (int q = 0; q < 8; ++q) pk[cc][q] = 0u;
        const float* w2b = w2 + e2 * 2048 + colq;   // w2[e][i][c]
        #pragma unroll
        for (int i = 0; i < 16; ++i) {
            float4 q4 = *(const float4*)(w2b + i * 128);
            unsigned sh = (i & 1) * 16;
            pk[0][i >> 1] |= (unsigned)f2bf(q4.x) << sh;
            pk[1][i >> 1] |= (unsigned)f2bf(q4.y) << sh;
            pk[2][i >> 1] |= (unsigned)f2bf(q4.z) << sh;
            pk[3][i >> 1] |= (unsigned)f2bf(q4.w) << sh;
        }
    }

    // w1 -> w1t[p][c] bf16 (p = e*16+i), swizzled
    {
        const int p = t & 127, ch = t >> 7;
        const float* w1b = w1 + (p >> 4) * 2048 + (p & 15);   // w1[e][c][i]
        #pragma unroll
        for (int cc = 0; cc < 8; ++cc) {
            short8 v;
            #pragma unroll
            for (int j = 0; j < 8; ++j)
                v[j] = (short)f2bf(w1b[(ch * 64 + cc * 8 + j) * 16]);
            *(short8*)(pW + swz(p, ch * 8 + cc)) = v;
        }
    }

    // gate weights as A-operand fragments: lane tl = expert row (tl<8), k = c
    short8 gfr[4];
    float4 gb4;
    {
        #pragma unroll
        for (int ks = 0; ks < 4; ++ks)
            #pragma unroll
            for (int j = 0; j < 8; ++j) {
                float v = (tl < 8) ? gate_w[(32 * ks + 8 * ak + j) * 8 + tl] : 0.0f;
                gfr[ks][j] = (short)f2bf(v);
            }
        gb4 = *(const float4*)(gate_b + (ak & 1) * 4);
    }

    //---------------- LN in registers, xn -> LDS ----------------
    #pragma unroll
    for (int s = 0; s < 8; ++s) {
        float4 v = xv[s];
        float sm = v.x + v.y + v.z + v.w;
        float sq = v.x*v.x + v.y*v.y + v.z*v.z + v.w*v.w;
        #pragma unroll
        for (int m = 1; m < 32; m <<= 1) {
            sm += __shfl_xor(sm, m, 64);
            sq += __shfl_xor(sq, m, 64);
        }
        float mu = sm * (1.0f / 128.0f);
        float var = sq * (1.0f / 128.0f) - mu * mu;
        float rs = rsqrtf(var + 1e-5f);
        float n0 = (v.x - mu) * rs * g4.x + b4.x;
        float n1 = (v.y - mu) * rs * g4.y + b4.y;
        float n2 = (v.z - mu) * rs * g4.z + b4.z;
        float n3 = (v.w - mu) * rs * g4.w + b4.w;
        unsigned lo = (unsigned)f2bf(n0) | ((unsigned)f2bf(n1) << 16);
        unsigned hi = (unsigned)f2bf(n2) | ((unsigned)f2bf(n3) << 16);
        unsigned long long dvv = (unsigned long long)lo | ((unsigned long long)hi << 32);
        int row = s * 8 + rsub;
        *(unsigned long long*)(pXY + swz(row, colq >> 3) + (colq & 7) * 2) = dvv;
    }

    bar_lds();   // bar1: xn + w1t ready

    const f32x4 zero4 = {0.f, 0.f, 0.f, 0.f};
    const short8 zfrag = {0, 0, 0, 0, 0, 0, 0, 0};

    // xn fragments (B-operand: lane tl = token col, k = c)
    short8 afr[4];
    #pragma unroll
    for (int ks = 0; ks < 4; ++ks)
        afr[ks] = *(const short8*)(pXY + swz(rb + tl, ks * 4 + ak));

    //---------------- gating (swapped): D[e][token] ----------------
    f32x4 accg = zero4;
    #pragma unroll
    for (int ks = 0; ks < 4; ++ks)
        accg = __builtin_amdgcn_mfma_f32_16x16x32_bf16(gfr[ks], afr[ks], accg, 0, 0, 0);

    const size_t trow = (size_t)(tok0 + rb + tl);
    {
        // lane holds logits for token trow, experts e = ak*4 + r (valid ak<2)
        float lg0 = accg[0] + gb4.x;
        float lg1 = accg[1] + gb4.y;
        float lg2 = accg[2] + gb4.z;
        float lg3 = accg[3] + gb4.w;
        if (ak < 2) {
            f32x4 lgv = {lg0, lg1, lg2, lg3};
            __builtin_nontemporal_store(lgv, (f32x4*)(out + O1_OFF + trow * 8 + ak * 4));
        }
        float mx = fmaxf(fmaxf(lg0, lg1), fmaxf(lg2, lg3));
        mx = fmaxf(mx, __shfl_xor(mx, 16, 64));
        float ex0 = __expf(lg0 - mx), ex1 = __expf(lg1 - mx);
        float ex2 = __expf(lg2 - mx), ex3 = __expf(lg3 - mx);
        float sm = ex0 + ex1 + ex2 + ex3;
        sm += __shfl_xor(sm, 16, 64);
        float inv = 1.0f / sm;
        if (ak < 2) {
            f32x4 pv = {ex0 * inv, ex1 * inv, ex2 * inv, ex3 * inv};
            *(f32x4*)(pRW + (rb + tl) * 8 + ak * 4) = pv;
        }
    }

    //---------------- stage B (swapped): y^T = (xn @ w1)^T ----------------
    f32x4 accb[8];
    #pragma unroll
    for (int nt = 0; nt < 8; ++nt) accb[nt] = zero4;
    #pragma unroll
    for (int ks = 0; ks < 4; ++ks)
        #pragma unroll
        for (int nt = 0; nt < 8; ++nt) {
            short8 wfr = *(const short8*)(pW + swz(nt * 16 + tl, ks * 4 + ak));
            accb[nt] = __builtin_amdgcn_mfma_f32_16x16x32_bf16(wfr, afr[ks], accb[nt], 0, 0, 0);
        }

    // exact-erf GELU; lane holds token tl, ei = nt*16 + ak*4 + r -> 8B packed write
    #pragma unroll
    for (int nt = 0; nt < 8; ++nt) {
        float y0 = accb[nt][0], y1 = accb[nt][1], y2 = accb[nt][2], y3 = accb[nt][3];
        y0 = 0.5f * y0 * (1.0f + erff(y0 * 0.70710678118654752f));
        y1 = 0.5f * y1 * (1.0f + erff(y1 * 0.70710678118654752f));
        y2 = 0.5f * y2 * (1.0f + erff(y2 * 0.70710678118654752f));
        y3 = 0.5f * y3 * (1.0f + erff(y3 * 0.70710678118654752f));
        unsigned lo = (unsigned)f2bf(y0) | ((unsigned)f2bf(y1) << 16);
        unsigned hi = (unsigned)f2bf(y2) | ((unsigned)f2bf(y3) << 16);
        unsigned long long dv = (unsigned long long)lo | ((unsigned long long)hi << 32);
        *(unsigned long long*)(pXY + swz(rb + tl, nt * 2 + (ak >> 1)) + (ak & 1) * 8) = dv;
    }

    bar_lds();   // bar2: all stage-B w1t reads done -> w1t region reusable

    // staged w2 -> w2t[(e,c)][i] bf16, chunk' = (rc*2+half) ^ ((c>>2)&3)
    #pragma unroll
    for (int cc = 0; cc < 4; ++cc) {
        int c = colq + cc;
        int rc = e2 * 128 + c;
        int a = (c >> 2) & 3;
        *(uint4*)(pW + (((rc * 2 + 0) ^ a) << 4)) =
            make_uint4(pk[cc][0], pk[cc][1], pk[cc][2], pk[cc][3]);
        *(uint4*)(pW + (((rc * 2 + 1) ^ a) << 4)) =
            make_uint4(pk[cc][4], pk[cc][5], pk[cc][6], pk[cc][7]);
    }

    bar_lds();   // bar3: w2t + y ready

    // routing weights for this lane's token (8 floats)
    f32x4 rwa = *(const f32x4*)(pRW + (rb + tl) * 8);
    f32x4 rwb = *(const f32x4*)(pRW + (rb + tl) * 8 + 4);

    //---------------- P4: swapped expert GEMM -> direct f32 stores ----------
    f32x4 agg[8];
    #pragma unroll
    for (int nt = 0; nt < 8; ++nt) agg[nt] = zero4;

    float* o2b = out + O2_OFF + trow * 1024 + ak * 4;
    #pragma unroll
    for (int e = 0; e < 8; ++e) {
        float rwe = (e < 4) ? rwa[e] : rwb[e - 4];
        short8 ylo = *(const short8*)(pXY + swz(rb + tl, 2 * e + (ak & 1)));
        short8 yf = (ak < 2) ? ylo : zfrag;          // K=16 padded to 32
        #pragma unroll
        for (int nt = 0; nt < 8; ++nt) {
            int c = nt * 16 + tl;
            int a = (c >> 2) & 3;
            short8 blo = *(const short8*)(pW + e * 4096 + (((c * 2 + (ak & 1)) ^ a) << 4));
            short8 bf = (ak < 2) ? blo : zfrag;
            // A = w2 frag (rows = D-cols), B = y frag (cols = tokens)
            // D: lane tl = token, c = nt*16 + ak*4 + r  (4 consecutive floats!)
            f32x4 ot = __builtin_amdgcn_mfma_f32_16x16x32_bf16(bf, yf, zero4, 0, 0, 0);
            __builtin_nontemporal_store(ot, (f32x4*)(o2b + e * 128 + nt * 16));
            #pragma unroll
            for (int r = 0; r < 4; ++r)
                agg[nt][r] += rwe * ot[r];
        }
    }

    bar_lds();   // bar4: all waves' w2t reads done -> pW reusable for x (f32)

    //---------------- epilogue: x through pW (f32, swizzled 512B rows) -------
    #pragma unroll
    for (int s = 0; s < 8; ++s) {
        int row = s * 8 + rsub;
        *(float4*)(pW + row * 512 + (((t & 31) ^ (row & 7)) << 4)) = xv[s];
    }

    bar_lds();   // bar5: x tile ready row-major

    float* o0b = out + trow * 128 + ak * 4;
    const int row0 = rb + tl;
    #pragma unroll
    for (int nt = 0; nt < 8; ++nt) {
        int ch = nt * 4 + ak;
        f32x4 xr = *(const f32x4*)(pW + row0 * 512 + ((ch ^ (row0 & 7)) << 4));
        f32x4 o = xr + agg[nt];
        __builtin_nontemporal_store(o, (f32x4*)(o0b + nt * 16));
    }
}

extern "C" void kernel_launch(void* const* d_in, const int* in_sizes, int n_in,
                              void* d_out, int out_size, void* d_ws, size_t ws_size,
                              hipStream_t stream) {
    const float* x      = (const float*)d_in[0];
    const float* ln_g   = (const float*)d_in[1];
    const float* ln_b   = (const float*)d_in[2];
    const float* gate_w = (const float*)d_in[3];
    const float* gate_b = (const float*)d_in[4];
    const float* w1     = (const float*)d_in[5];
    const float* w2     = (const float*)d_in[6];
    float* out = (float*)d_out;
    (void)in_sizes; (void)n_in; (void)out_size; (void)d_ws; (void)ws_size;
    moe_fused<<<dim3(1024), dim3(256), 0, stream>>>(x, ln_g, ln_b, gate_w, gate_b, w1, w2, out);
}

// Round 2
// 102.661 us; speedup vs baseline: 1.2252x; 1.2252x over previous
//
#include <hip/hip_runtime.h>
#include <math.h>

// Problem: B=8, T=8192, D=128, E=8, I=16.  BT = 65536 tokens.
// Outputs concatenated f32: out0 [BT,128] | out1 [BT,8] | out2 [BT,8,128]
#define O1_OFF 8388608
#define O2_OFF 8912896

typedef __attribute__((ext_vector_type(8))) short short8;
typedef __attribute__((ext_vector_type(4))) float f32x4;

static __device__ __forceinline__ unsigned short f2bf(float f) {
    unsigned u = __builtin_bit_cast(unsigned, f);
    u = (u + 0x7fffu + ((u >> 16) & 1u)) >> 16;   // RNE
    return (unsigned short)u;
}

// swizzled byte offset inside a [rows][16 x 16B-chunks] LDS region (256B rows)
static __device__ __forceinline__ int swz(int row, int chunk) {
    return row * 256 + ((chunk ^ (row & 7)) << 4);
}

// LDS-only barrier: does NOT drain vmcnt -> global stores stay in flight.
static __device__ __forceinline__ void bar_lds() {
    asm volatile("s_waitcnt lgkmcnt(0)" ::: "memory");
    __builtin_amdgcn_s_barrier();
    asm volatile("" ::: "memory");
}

__global__ __launch_bounds__(256, 2) void moe_fused(
    const float* __restrict__ x, const float* __restrict__ ln_g,
    const float* __restrict__ ln_b, const float* __restrict__ gate_w,
    const float* __restrict__ gate_b, const float* __restrict__ w1,
    const float* __restrict__ w2, float* __restrict__ out)
{
    // 50 KB: 2 blocks/CU (VGPR cap 256 -> no spills)
    __shared__ __align__(16) char smem[51200];
    char* pXY = smem;                      // 16KB: xn (bf16) -> y (bf16)
    char* pW  = smem + 16384;              // 32KB: w1t -> w2t -> x (f32)
    float* pRW = (float*)(smem + 49152);   // 2KB: routing weights [64][8] f32

    const int t = threadIdx.x;
    const int l = t & 63;
    const int w = t >> 6;
    const int tok0 = blockIdx.x * 64;

    const int colq = (t & 31) * 4;   // P0-layout columns
    const int rsub = t >> 5;         // P0-layout row sub-index

    const int rb = w * 16;           // wave's 16 token rows
    const int tl = l & 15;           // lane's token (D-layout col after swap)
    const int ak = l >> 4;           // MFMA k-subgroup / D-layout row group

    //---------------- P0: global loads + staging ----------------
    float4 xv[8];                    // x tile, held in regs to the end
    {
        const float* xb = x + (size_t)tok0 * 128;
        #pragma unroll
        for (int s = 0; s < 8; ++s)
            xv[s] = *(const float4*)(xb + s * 1024 + t * 4);
    }
    float4 g4 = *(const float4*)(ln_g + colq);
    float4 b4 = *(const float4*)(ln_b + colq);

    // w2 staged in registers (bf16-packed) until w1t region is free (bar2)
    const int e2 = t >> 5;
    unsigned pk[4][8];
    {
        #pragma unroll
        for (int cc = 0; cc < 4; ++cc)
            #pragma unroll
            for (int q = 0; q < 8; ++q) pk[cc][q] = 0u;
        const float* w2b = w2 + e2 * 2048 + colq;   // w2[e][i][c]
        #pragma unroll
        for (int i = 0; i < 16; ++i) {
            float4 q4 = *(const float4*)(w2b + i * 128);
            unsigned sh = (i & 1) * 16;
            pk[0][i >> 1] |= (unsigned)f2bf(q4.x) << sh;
            pk[1][i >> 1] |= (unsigned)f2bf(q4.y) << sh;
            pk[2][i >> 1] |= (unsigned)f2bf(q4.z) << sh;
            pk[3][i >> 1] |= (unsigned)f2bf(q4.w) << sh;
        }
    }

    // w1 -> w1t[p][c] bf16 (p = e*16+i), swizzled
    {
        const int p = t & 127, ch = t >> 7;
        const float* w1b = w1 + (p >> 4) * 2048 + (p & 15);   // w1[e][c][i]
        #pragma unroll
        for (int cc = 0; cc < 8; ++cc) {
            short8 v;
            #pragma unroll
            for (int j = 0; j < 8; ++j)
                v[j] = (short)f2bf(w1b[(ch * 64 + cc * 8 + j) * 16]);
            *(short8*)(pW + swz(p, ch * 8 + cc)) = v;
        }
    }

    // gate weights as A-operand fragments: lane tl = expert row (tl<8), k = c
    short8 gfr[4];
    float4 gb4;
    {
        #pragma unroll
        for (int ks = 0; ks < 4; ++ks)
            #pragma unroll
            for (int j = 0; j < 8; ++j) {
                float v = (tl < 8) ? gate_w[(32 * ks + 8 * ak + j) * 8 + tl] : 0.0f;
                gfr[ks][j] = (short)f2bf(v);
            }
        gb4 = *(const float4*)(gate_b + (ak & 1) * 4);
    }

    //---------------- LN in registers, xn -> LDS ----------------
    #pragma unroll
    for (int s = 0; s < 8; ++s) {
        float4 v = xv[s];
        float sm = v.x + v.y + v.z + v.w;
        float sq = v.x*v.x + v.y*v.y + v.z*v.z + v.w*v.w;
        #pragma unroll
        for (int m = 1; m < 32; m <<= 1) {
            sm += __shfl_xor(sm, m, 64);
            sq += __shfl_xor(sq, m, 64);
        }
        float mu = sm * (1.0f / 128.0f);
        float var = sq * (1.0f / 128.0f) - mu * mu;
        float rs = rsqrtf(var + 1e-5f);
        float n0 = (v.x - mu) * rs * g4.x + b4.x;
        float n1 = (v.y - mu) * rs * g4.y + b4.y;
        float n2 = (v.z - mu) * rs * g4.z + b4.z;
        float n3 = (v.w - mu) * rs * g4.w + b4.w;
        unsigned lo = (unsigned)f2bf(n0) | ((unsigned)f2bf(n1) << 16);
        unsigned hi = (unsigned)f2bf(n2) | ((unsigned)f2bf(n3) << 16);
        unsigned long long dvv = (unsigned long long)lo | ((unsigned long long)hi << 32);
        int row = s * 8 + rsub;
        *(unsigned long long*)(pXY + swz(row, colq >> 3) + (colq & 7) * 2) = dvv;
    }

    bar_lds();   // bar1: xn + w1t ready

    const f32x4 zero4 = {0.f, 0.f, 0.f, 0.f};
    const short8 zfrag = {0, 0, 0, 0, 0, 0, 0, 0};

    // xn fragments (B-operand: lane tl = token col, k = c)
    short8 afr[4];
    #pragma unroll
    for (int ks = 0; ks < 4; ++ks)
        afr[ks] = *(const short8*)(pXY + swz(rb + tl, ks * 4 + ak));

    //---------------- gating (swapped): D[e][token] ----------------
    f32x4 accg = zero4;
    #pragma unroll
    for (int ks = 0; ks < 4; ++ks)
        accg = __builtin_amdgcn_mfma_f32_16x16x32_bf16(gfr[ks], afr[ks], accg, 0, 0, 0);

    const size_t trow = (size_t)(tok0 + rb + tl);
    {
        // lane holds logits for token trow, experts e = ak*4 + r (valid ak<2)
        float lg0 = accg[0] + gb4.x;
        float lg1 = accg[1] + gb4.y;
        float lg2 = accg[2] + gb4.z;
        float lg3 = accg[3] + gb4.w;
        if (ak < 2) {
            f32x4 lgv = {lg0, lg1, lg2, lg3};
            *(f32x4*)(out + O1_OFF + trow * 8 + ak * 4) = lgv;
        }
        float mx = fmaxf(fmaxf(lg0, lg1), fmaxf(lg2, lg3));
        mx = fmaxf(mx, __shfl_xor(mx, 16, 64));
        float ex0 = __expf(lg0 - mx), ex1 = __expf(lg1 - mx);
        float ex2 = __expf(lg2 - mx), ex3 = __expf(lg3 - mx);
        float sm = ex0 + ex1 + ex2 + ex3;
        sm += __shfl_xor(sm, 16, 64);
        float inv = 1.0f / sm;
        if (ak < 2) {
            f32x4 pv = {ex0 * inv, ex1 * inv, ex2 * inv, ex3 * inv};
            *(f32x4*)(pRW + (rb + tl) * 8 + ak * 4) = pv;
        }
    }

    //---------------- stage B (swapped): y^T = (xn @ w1)^T ----------------
    f32x4 accb[8];
    #pragma unroll
    for (int nt = 0; nt < 8; ++nt) accb[nt] = zero4;
    #pragma unroll
    for (int ks = 0; ks < 4; ++ks)
        #pragma unroll
        for (int nt = 0; nt < 8; ++nt) {
            short8 wfr = *(const short8*)(pW + swz(nt * 16 + tl, ks * 4 + ak));
            accb[nt] = __builtin_amdgcn_mfma_f32_16x16x32_bf16(wfr, afr[ks], accb[nt], 0, 0, 0);
        }

    // exact-erf GELU; lane holds token tl, ei = nt*16 + ak*4 + r -> 8B packed write
    #pragma unroll
    for (int nt = 0; nt < 8; ++nt) {
        float y0 = accb[nt][0], y1 = accb[nt][1], y2 = accb[nt][2], y3 = accb[nt][3];
        y0 = 0.5f * y0 * (1.0f + erff(y0 * 0.70710678118654752f));
        y1 = 0.5f * y1 * (1.0f + erff(y1 * 0.70710678118654752f));
        y2 = 0.5f * y2 * (1.0f + erff(y2 * 0.70710678118654752f));
        y3 = 0.5f * y3 * (1.0f + erff(y3 * 0.70710678118654752f));
        unsigned lo = (unsigned)f2bf(y0) | ((unsigned)f2bf(y1) << 16);
        unsigned hi = (unsigned)f2bf(y2) | ((unsigned)f2bf(y3) << 16);
        unsigned long long dv = (unsigned long long)lo | ((unsigned long long)hi << 32);
        *(unsigned long long*)(pXY + swz(rb + tl, nt * 2 + (ak >> 1)) + (ak & 1) * 8) = dv;
    }

    bar_lds();   // bar2: all stage-B w1t reads done -> w1t region reusable

    // staged w2 -> w2t[(e,c)][i] bf16, chunk' = (rc*2+half) ^ ((c>>2)&3)
    #pragma unroll
    for (int cc = 0; cc < 4; ++cc) {
        int c = colq + cc;
        int rc = e2 * 128 + c;
        int a = (c >> 2) & 3;
        *(uint4*)(pW + (((rc * 2 + 0) ^ a) << 4)) =
            make_uint4(pk[cc][0], pk[cc][1], pk[cc][2], pk[cc][3]);
        *(uint4*)(pW + (((rc * 2 + 1) ^ a) << 4)) =
            make_uint4(pk[cc][4], pk[cc][5], pk[cc][6], pk[cc][7]);
    }

    bar_lds();   // bar3: w2t + y ready

    // routing weights for this lane's token (8 floats)
    f32x4 rwa = *(const f32x4*)(pRW + (rb + tl) * 8);
    f32x4 rwb = *(const f32x4*)(pRW + (rb + tl) * 8 + 4);

    //---------------- P4: swapped expert GEMM -> direct f32 stores ----------
    f32x4 agg[8];
    #pragma unroll
    for (int nt = 0; nt < 8; ++nt) agg[nt] = zero4;

    float* o2b = out + O2_OFF + trow * 1024 + ak * 4;
    #pragma unroll
    for (int e = 0; e < 8; ++e) {
        float rwe = (e < 4) ? rwa[e] : rwb[e - 4];
        short8 ylo = *(const short8*)(pXY + swz(rb + tl, 2 * e + (ak & 1)));
        short8 yf = (ak < 2) ? ylo : zfrag;          // K=16 padded to 32
        #pragma unroll
        for (int nt = 0; nt < 8; ++nt) {
            int c = nt * 16 + tl;
            int a = (c >> 2) & 3;
            short8 blo = *(const short8*)(pW + e * 4096 + (((c * 2 + (ak & 1)) ^ a) << 4));
            short8 bf = (ak < 2) ? blo : zfrag;
            // A = w2 frag (rows = D-cols), B = y frag (cols = tokens)
            // D: lane tl = token, c = nt*16 + ak*4 + r  (4 consecutive floats!)
            f32x4 ot = __builtin_amdgcn_mfma_f32_16x16x32_bf16(bf, yf, zero4, 0, 0, 0);
            *(f32x4*)(o2b + e * 128 + nt * 16) = ot;
            #pragma unroll
            for (int r = 0; r < 4; ++r)
                agg[nt][r] += rwe * ot[r];
        }
    }

    bar_lds();   // bar4: all waves' w2t reads done -> pW reusable for x (f32)

    //---------------- epilogue: x through pW (f32, swizzled 512B rows) -------
    #pragma unroll
    for (int s = 0; s < 8; ++s) {
        int row = s * 8 + rsub;
        *(float4*)(pW + row * 512 + (((t & 31) ^ (row & 7)) << 4)) = xv[s];
    }

    bar_lds();   // bar5: x tile ready row-major

    float* o0b = out + trow * 128 + ak * 4;
    const int row0 = rb + tl;
    #pragma unroll
    for (int nt = 0; nt < 8; ++nt) {
        int ch = nt * 4 + ak;
        f32x4 xr = *(const f32x4*)(pW + row0 * 512 + ((ch ^ (row0 & 7)) << 4));
        f32x4 o = xr + agg[nt];
        *(f32x4*)(o0b + nt * 16) = o;
    }
}

extern "C" void kernel_launch(void* const* d_in, const int* in_sizes, int n_in,
                              void* d_out, int out_size, void* d_ws, size_t ws_size,
                              hipStream_t stream) {
    const float* x      = (const float*)d_in[0];
    const float* ln_g   = (const float*)d_in[1];
    const float* ln_b   = (const float*)d_in[2];
    const float* gate_w = (const float*)d_in[3];
    const float* gate_b = (const float*)d_in[4];
    const float* w1     = (const float*)d_in[5];
    const float* w2     = (const float*)d_in[6];
    float* out = (float*)d_out;
    (void)in_sizes; (void)n_in; (void)out_size; (void)d_ws; (void)ws_size;
    moe_fused<<<dim3(1024), dim3(256), 0, stream>>>(x, ln_g, ln_b, gate_w, gate_b, w1, w2, out);
}

// Round 3
// 94.281 us; speedup vs baseline: 1.3340x; 1.0889x over previous
//
#include <hip/hip_runtime.h>
#include <math.h>

// Problem: B=8, T=8192, D=128, E=8, I=16.  BT = 65536 tokens.
// Outputs concatenated f32: out0 [BT,128] | out1 [BT,8] | out2 [BT,8,128]
#define O1_OFF 8388608
#define O2_OFF 8912896

typedef __attribute__((ext_vector_type(8))) short short8;
typedef __attribute__((ext_vector_type(4))) float f32x4;

static __device__ __forceinline__ unsigned short f2bf(float f) {
    unsigned u = __builtin_bit_cast(unsigned, f);
    u = (u + 0x7fffu + ((u >> 16) & 1u)) >> 16;   // RNE
    return (unsigned short)u;
}

// swizzled byte offset inside a [rows][16 x 16B-chunks] LDS region (256B rows)
static __device__ __forceinline__ int swz(int row, int chunk) {
    return row * 256 + ((chunk ^ (row & 7)) << 4);
}

// LDS-only barrier: does NOT drain vmcnt -> global stores stay in flight.
static __device__ __forceinline__ void bar_lds() {
    asm volatile("s_waitcnt lgkmcnt(0)" ::: "memory");
    __builtin_amdgcn_s_barrier();
    asm volatile("" ::: "memory");
}

// within-wave LDS fence: drain DS ops + block compiler (TBAA) reordering
static __device__ __forceinline__ void fence_lds() {
    asm volatile("s_waitcnt lgkmcnt(0)" ::: "memory");
}

__global__ __launch_bounds__(256, 2) void moe_fused(
    const float* __restrict__ x, const float* __restrict__ ln_g,
    const float* __restrict__ ln_b, const float* __restrict__ gate_w,
    const float* __restrict__ gate_b, const float* __restrict__ w1,
    const float* __restrict__ w2, float* __restrict__ out)
{
    // 66 KB: 2 blocks/CU, VGPR cap 256
    __shared__ __align__(16) char smem[67584];
    char* pXY = smem;                      // 16KB: xn (bf16) -> y (bf16)
    char* pW  = smem + 16384;              // 32KB: w1t -> w2t -> agg (f32)
    char* pTR = smem + 49152;              // 16KB: f32 transpose buffer (out2 half-tiles)
    float* pRW = (float*)(smem + 65536);   // 2KB: routing weights [64][8] f32

    const int t = threadIdx.x;
    const int l = t & 63;
    const int w = t >> 6;
    const int tok0 = blockIdx.x * 64;

    const int colq = (t & 31) * 4;   // P0-layout columns
    const int rsub = t >> 5;         // P0-layout row sub-index

    const int rb = w * 16;           // wave's 16 token rows
    const int tl = l & 15;           // lane's token (D-layout col after swap)
    const int ak = l >> 4;           // MFMA k-subgroup / D-layout row group
    const int l4 = l >> 4;           // row sub for transpose readback
    const int cl = l & 15;           // chunk for transpose readback

    //---------------- P0: global loads + staging ----------------
    float4 xv[8];                    // x tile, held in regs to the end
    {
        const float* xb = x + (size_t)tok0 * 128;
        #pragma unroll
        for (int s = 0; s < 8; ++s)
            xv[s] = *(const float4*)(xb + s * 1024 + t * 4);
    }
    float4 g4 = *(const float4*)(ln_g + colq);
    float4 b4 = *(const float4*)(ln_b + colq);

    // w2 staged in registers (bf16-packed) until w1t region is free (bar2)
    const int e2 = t >> 5;
    unsigned pk[4][8];
    {
        #pragma unroll
        for (int cc = 0; cc < 4; ++cc)
            #pragma unroll
            for (int q = 0; q < 8; ++q) pk[cc][q] = 0u;
        const float* w2b = w2 + e2 * 2048 + colq;   // w2[e][i][c]
        #pragma unroll
        for (int i = 0; i < 16; ++i) {
            float4 q4 = *(const float4*)(w2b + i * 128);
            unsigned sh = (i & 1) * 16;
            pk[0][i >> 1] |= (unsigned)f2bf(q4.x) << sh;
            pk[1][i >> 1] |= (unsigned)f2bf(q4.y) << sh;
            pk[2][i >> 1] |= (unsigned)f2bf(q4.z) << sh;
            pk[3][i >> 1] |= (unsigned)f2bf(q4.w) << sh;
        }
    }

    // w1 -> w1t[p][c] bf16 (p = e*16+i), swizzled
    {
        const int p = t & 127, ch = t >> 7;
        const float* w1b = w1 + (p >> 4) * 2048 + (p & 15);   // w1[e][c][i]
        #pragma unroll
        for (int cc = 0; cc < 8; ++cc) {
            short8 v;
            #pragma unroll
            for (int j = 0; j < 8; ++j)
                v[j] = (short)f2bf(w1b[(ch * 64 + cc * 8 + j) * 16]);
            *(short8*)(pW + swz(p, ch * 8 + cc)) = v;
        }
    }

    // gate weights as A-operand fragments: lane tl = expert row (tl<8), k = c
    short8 gfr[4];
    float4 gb4;
    {
        #pragma unroll
        for (int ks = 0; ks < 4; ++ks)
            #pragma unroll
            for (int j = 0; j < 8; ++j) {
                float v = (tl < 8) ? gate_w[(32 * ks + 8 * ak + j) * 8 + tl] : 0.0f;
                gfr[ks][j] = (short)f2bf(v);
            }
        gb4 = *(const float4*)(gate_b + (ak & 1) * 4);
    }

    //---------------- LN in registers, xn -> LDS ----------------
    #pragma unroll
    for (int s = 0; s < 8; ++s) {
        float4 v = xv[s];
        float sm = v.x + v.y + v.z + v.w;
        float sq = v.x*v.x + v.y*v.y + v.z*v.z + v.w*v.w;
        #pragma unroll
        for (int m = 1; m < 32; m <<= 1) {
            sm += __shfl_xor(sm, m, 64);
            sq += __shfl_xor(sq, m, 64);
        }
        float mu = sm * (1.0f / 128.0f);
        float var = sq * (1.0f / 128.0f) - mu * mu;
        float rs = rsqrtf(var + 1e-5f);
        float n0 = (v.x - mu) * rs * g4.x + b4.x;
        float n1 = (v.y - mu) * rs * g4.y + b4.y;
        float n2 = (v.z - mu) * rs * g4.z + b4.z;
        float n3 = (v.w - mu) * rs * g4.w + b4.w;
        unsigned lo = (unsigned)f2bf(n0) | ((unsigned)f2bf(n1) << 16);
        unsigned hi = (unsigned)f2bf(n2) | ((unsigned)f2bf(n3) << 16);
        unsigned long long dvv = (unsigned long long)lo | ((unsigned long long)hi << 32);
        int row = s * 8 + rsub;
        *(unsigned long long*)(pXY + swz(row, colq >> 3) + (colq & 7) * 2) = dvv;
    }

    bar_lds();   // bar1: xn + w1t ready

    const f32x4 zero4 = {0.f, 0.f, 0.f, 0.f};
    const short8 zfrag = {0, 0, 0, 0, 0, 0, 0, 0};

    // xn fragments (B-operand: lane tl = token col, k = c)
    short8 afr[4];
    #pragma unroll
    for (int ks = 0; ks < 4; ++ks)
        afr[ks] = *(const short8*)(pXY + swz(rb + tl, ks * 4 + ak));

    //---------------- gating (swapped): D[e][token] ----------------
    f32x4 accg = zero4;
    #pragma unroll
    for (int ks = 0; ks < 4; ++ks)
        accg = __builtin_amdgcn_mfma_f32_16x16x32_bf16(gfr[ks], afr[ks], accg, 0, 0, 0);

    const size_t trow = (size_t)(tok0 + rb + tl);
    {
        // lane holds logits for token trow, experts e = ak*4 + r (valid ak<2)
        float lg0 = accg[0] + gb4.x;
        float lg1 = accg[1] + gb4.y;
        float lg2 = accg[2] + gb4.z;
        float lg3 = accg[3] + gb4.w;
        if (ak < 2) {
            f32x4 lgv = {lg0, lg1, lg2, lg3};
            *(f32x4*)(out + O1_OFF + trow * 8 + ak * 4) = lgv;
        }
        float mx = fmaxf(fmaxf(lg0, lg1), fmaxf(lg2, lg3));
        mx = fmaxf(mx, __shfl_xor(mx, 16, 64));
        float ex0 = __expf(lg0 - mx), ex1 = __expf(lg1 - mx);
        float ex2 = __expf(lg2 - mx), ex3 = __expf(lg3 - mx);
        float sm = ex0 + ex1 + ex2 + ex3;
        sm += __shfl_xor(sm, 16, 64);
        float inv = 1.0f / sm;
        if (ak < 2) {
            f32x4 pv = {ex0 * inv, ex1 * inv, ex2 * inv, ex3 * inv};
            *(f32x4*)(pRW + (rb + tl) * 8 + ak * 4) = pv;
        }
    }

    //---------------- stage B (swapped): y^T = (xn @ w1)^T ----------------
    f32x4 accb[8];
    #pragma unroll
    for (int nt = 0; nt < 8; ++nt) accb[nt] = zero4;
    #pragma unroll
    for (int ks = 0; ks < 4; ++ks)
        #pragma unroll
        for (int nt = 0; nt < 8; ++nt) {
            short8 wfr = *(const short8*)(pW + swz(nt * 16 + tl, ks * 4 + ak));
            accb[nt] = __builtin_amdgcn_mfma_f32_16x16x32_bf16(wfr, afr[ks], accb[nt], 0, 0, 0);
        }

    // exact-erf GELU; lane holds token tl, ei = nt*16 + ak*4 + r -> 8B packed write
    #pragma unroll
    for (int nt = 0; nt < 8; ++nt) {
        float y0 = accb[nt][0], y1 = accb[nt][1], y2 = accb[nt][2], y3 = accb[nt][3];
        y0 = 0.5f * y0 * (1.0f + erff(y0 * 0.70710678118654752f));
        y1 = 0.5f * y1 * (1.0f + erff(y1 * 0.70710678118654752f));
        y2 = 0.5f * y2 * (1.0f + erff(y2 * 0.70710678118654752f));
        y3 = 0.5f * y3 * (1.0f + erff(y3 * 0.70710678118654752f));
        unsigned lo = (unsigned)f2bf(y0) | ((unsigned)f2bf(y1) << 16);
        unsigned hi = (unsigned)f2bf(y2) | ((unsigned)f2bf(y3) << 16);
        unsigned long long dv = (unsigned long long)lo | ((unsigned long long)hi << 32);
        *(unsigned long long*)(pXY + swz(rb + tl, nt * 2 + (ak >> 1)) + (ak & 1) * 8) = dv;
    }

    bar_lds();   // bar2: all stage-B w1t reads done -> w1t region reusable

    // staged w2 -> w2t[(e,c)][i] bf16, chunk' = (rc*2+half) ^ ((c>>2)&3)
    #pragma unroll
    for (int cc = 0; cc < 4; ++cc) {
        int c = colq + cc;
        int rc = e2 * 128 + c;
        int a = (c >> 2) & 3;
        *(uint4*)(pW + (((rc * 2 + 0) ^ a) << 4)) =
            make_uint4(pk[cc][0], pk[cc][1], pk[cc][2], pk[cc][3]);
        *(uint4*)(pW + (((rc * 2 + 1) ^ a) << 4)) =
            make_uint4(pk[cc][4], pk[cc][5], pk[cc][6], pk[cc][7]);
    }

    bar_lds();   // bar3: w2t + y ready

    // routing weights for this lane's token (8 floats)
    f32x4 rwa = *(const f32x4*)(pRW + (rb + tl) * 8);
    f32x4 rwb = *(const f32x4*)(pRW + (rb + tl) * 8 + 4);

    //---------------- P4: swapped expert GEMM -> f32 LDS transpose -> 256B stores
    f32x4 agg[8];
    #pragma unroll
    for (int nt = 0; nt < 8; ++nt) agg[nt] = zero4;

    // transpose write base: row = rb+tl (wave-private), chunk swizzle ^ tl
    char* trw = pTR + (rb + tl) * 256;
    // readback: row = rb + q*4 + l4, chunk cl ^ (row&15)
    const float* o2r = out + O2_OFF + (size_t)(tok0 + rb + l4) * 1024 + cl * 4;

    #pragma unroll
    for (int e = 0; e < 8; ++e) {
        float rwe = (e < 4) ? rwa[e] : rwb[e - 4];
        short8 ylo = *(const short8*)(pXY + swz(rb + tl, 2 * e + (ak & 1)));
        short8 yf = (ak < 2) ? ylo : zfrag;          // K=16 padded to 32
        #pragma unroll
        for (int h = 0; h < 2; ++h) {
            // compute 4 column-blocks (64 cols) and write f32x4 to pTR
            #pragma unroll
            for (int ntl = 0; ntl < 4; ++ntl) {
                int nt = h * 4 + ntl;
                int c = nt * 16 + tl;
                int a = (c >> 2) & 3;
                short8 blo = *(const short8*)(pW + e * 4096 + (((c * 2 + (ak & 1)) ^ a) << 4));
                short8 bf = (ak < 2) ? blo : zfrag;
                // D: lane tl = token, cols c = nt*16 + ak*4 + r
                f32x4 ot = __builtin_amdgcn_mfma_f32_16x16x32_bf16(bf, yf, zero4, 0, 0, 0);
                #pragma unroll
                for (int r = 0; r < 4; ++r)
                    agg[nt][r] += rwe * ot[r];
                int chk = (ntl * 4 + ak) ^ tl;       // 16B chunk within 256B half-row
                *(f32x4*)(trw + (chk << 4)) = ot;
            }
            fence_lds();   // wave-private rows: waitcnt only, no barrier
            // read back row-major: 4 rows x 256B contiguous per instruction
            #pragma unroll
            for (int q = 0; q < 4; ++q) {
                int row = q * 4 + l4;                // row within wave tile (&15)
                int chk = cl ^ row;
                f32x4 v = *(const f32x4*)(pTR + (rb + row) * 256 + (chk << 4));
                *(f32x4*)(o2r + (size_t)q * 4096 + e * 128 + h * 64) = v;
            }
            asm volatile("" ::: "memory");   // keep next half's writes after these reads
        }
    }

    bar_lds();   // bar4: all waves' w2t reads done -> pW reusable for agg (f32)

    //---------------- epilogue: agg transpose through pW (f32, 512B rows) ----
    #pragma unroll
    for (int nt = 0; nt < 8; ++nt) {
        int chk = (nt * 4 + ak) ^ tl;                // 16B chunk within 512B row
        *(f32x4*)(pW + (rb + tl) * 512 + (chk << 4)) = agg[nt];
    }

    bar_lds();   // bar5: agg tile ready (block-wide rows)

    #pragma unroll
    for (int s = 0; s < 8; ++s) {
        int row = s * 8 + rsub;
        int chk = (t & 31) ^ (row & 15);
        f32x4 a4 = *(const f32x4*)(pW + row * 512 + (chk << 4));
        float4 o;
        o.x = xv[s].x + a4[0];
        o.y = xv[s].y + a4[1];
        o.z = xv[s].z + a4[2];
        o.w = xv[s].w + a4[3];
        *(float4*)(out + (size_t)(tok0 + row) * 128 + colq) = o;
    }
}

extern "C" void kernel_launch(void* const* d_in, const int* in_sizes, int n_in,
                              void* d_out, int out_size, void* d_ws, size_t ws_size,
                              hipStream_t stream) {
    const float* x      = (const float*)d_in[0];
    const float* ln_g   = (const float*)d_in[1];
    const float* ln_b   = (const float*)d_in[2];
    const float* gate_w = (const float*)d_in[3];
    const float* gate_b = (const float*)d_in[4];
    const float* w1     = (const float*)d_in[5];
    const float* w2     = (const float*)d_in[6];
    float* out = (float*)d_out;
    (void)in_sizes; (void)n_in; (void)out_size; (void)d_ws; (void)ws_size;
    moe_fused<<<dim3(1024), dim3(256), 0, stream>>>(x, ln_g, ln_b, gate_w, gate_b, w1, w2, out);
}

// Round 4
// 80.893 us; speedup vs baseline: 1.5548x; 1.1655x over previous
//
#include <hip/hip_runtime.h>
#include <math.h>

// Problem: B=8, T=8192, D=128, E=8, I=16.  BT = 65536 tokens.
// Outputs concatenated f32: out0 [BT,128] | out1 [BT,8] | out2 [BT,8,128]
#define O1_OFF 8388608
#define O2_OFF 8912896

typedef __attribute__((ext_vector_type(8))) short short8;
typedef __attribute__((ext_vector_type(4))) float f32x4;

static __device__ __forceinline__ unsigned short f2bf(float f) {
    unsigned u = __builtin_bit_cast(unsigned, f);
    u = (u + 0x7fffu + ((u >> 16) & 1u)) >> 16;   // RNE
    return (unsigned short)u;
}

// swizzled byte offset inside a [rows][16 x 16B-chunks] LDS region (weights/xn/y)
static __device__ __forceinline__ int swz(int row, int chunk) {
    return row * 256 + ((chunk ^ (row & 7)) << 4);
}

// transpose-region byte offset: [row 0..63][col 0..127] bf16, 256B/row.
static __device__ __forceinline__ int tswz(int row, int col) {
    int chunk = (col >> 3) ^ ((row >> 1) & 6);
    return row * 256 + (chunk << 4) + ((col & 7) << 1);
}

// LDS-only barrier: does NOT drain vmcnt -> global stores stay in flight.
static __device__ __forceinline__ void bar_lds() {
    asm volatile("s_waitcnt lgkmcnt(0)" ::: "memory");
    __builtin_amdgcn_s_barrier();
    asm volatile("" ::: "memory");
}

// within-wave LDS fence: drain DS ops + block compiler (TBAA) reordering
static __device__ __forceinline__ void fence_lds() {
    asm volatile("s_waitcnt lgkmcnt(0)" ::: "memory");
}

__global__ __launch_bounds__(256, 2) void moe_fused(
    const float* __restrict__ x, const float* __restrict__ ln_g,
    const float* __restrict__ ln_b, const float* __restrict__ gate_w,
    const float* __restrict__ gate_b, const float* __restrict__ w1,
    const float* __restrict__ w2, float* __restrict__ out)
{
    // 66 KB: 2 blocks/CU
    __shared__ __align__(16) char smem[67584];
    char* pXY = smem;                      // 16KB: xn (bf16), then y (bf16)
    char* pW  = smem + 16384;              // 32KB: w1t, then w2t, then agg f32
    char* pTR = smem + 49152;              // 16KB: bf16 transpose buffer (out2 tiles)
    float* pRW = (float*)(smem + 65536);   // 2KB: routing weights [64][8] f32

    const int t = threadIdx.x;
    const int l = t & 63;
    const int w = t >> 6;
    const int tok0 = blockIdx.x * 64;

    const int colq = (t & 31) * 4;   // P0-layout columns
    const int rsub = t >> 5;         // P0-layout row sub-index

    const int rb = w * 16;           // wave's 16 token rows
    const int col = l & 15;          // MFMA n / lane col (token index in tiles)
    const int ak = l >> 4;           // MFMA k-subgroup / token 4-row group
    const int arow = rb + col;

    //---------------- P0: global loads + staging ----------------
    float4 xv[8];                    // x tile, held in regs to the end
    {
        const float* xb = x + (size_t)tok0 * 128;
        #pragma unroll
        for (int s = 0; s < 8; ++s)
            xv[s] = *(const float4*)(xb + s * 1024 + t * 4);
    }
    float4 g4 = *(const float4*)(ln_g + colq);
    float4 b4 = *(const float4*)(ln_b + colq);

    // w2 staged in registers (bf16-packed) until w1t region is free (bar2)
    const int e2 = t >> 5;
    unsigned pk[4][8];
    {
        #pragma unroll
        for (int cc = 0; cc < 4; ++cc)
            #pragma unroll
            for (int q = 0; q < 8; ++q) pk[cc][q] = 0u;
        const float* w2b = w2 + e2 * 2048 + colq;   // w2[e][i][c]
        #pragma unroll
        for (int i = 0; i < 16; ++i) {
            float4 q4 = *(const float4*)(w2b + i * 128);
            unsigned sh = (i & 1) * 16;
            pk[0][i >> 1] |= (unsigned)f2bf(q4.x) << sh;
            pk[1][i >> 1] |= (unsigned)f2bf(q4.y) << sh;
            pk[2][i >> 1] |= (unsigned)f2bf(q4.z) << sh;
            pk[3][i >> 1] |= (unsigned)f2bf(q4.w) << sh;
        }
    }

    // w1 -> w1t[p][c] bf16 (p = e*16+i), swizzled
    {
        const int p = t & 127, ch = t >> 7;
        const float* w1b = w1 + (p >> 4) * 2048 + (p & 15);   // w1[e][c][i]
        #pragma unroll
        for (int cc = 0; cc < 8; ++cc) {
            short8 v;
            #pragma unroll
            for (int j = 0; j < 8; ++j)
                v[j] = (short)f2bf(w1b[(ch * 64 + cc * 8 + j) * 16]);
            *(short8*)(pW + swz(p, ch * 8 + cc)) = v;
        }
    }

    // gate weights as A-operand fragments: lane col = expert row (col<8), k = c
    short8 gfr[4];
    float4 gb4;
    {
        #pragma unroll
        for (int ks = 0; ks < 4; ++ks)
            #pragma unroll
            for (int j = 0; j < 8; ++j) {
                float v = (col < 8) ? gate_w[(32 * ks + 8 * ak + j) * 8 + col] : 0.0f;
                gfr[ks][j] = (short)f2bf(v);
            }
        gb4 = *(const float4*)(gate_b + (ak & 1) * 4);
    }

    //---------------- LN in registers, xn -> LDS ----------------
    #pragma unroll
    for (int s = 0; s < 8; ++s) {
        float4 v = xv[s];
        float sm = v.x + v.y + v.z + v.w;
        float sq = v.x*v.x + v.y*v.y + v.z*v.z + v.w*v.w;
        #pragma unroll
        for (int m = 1; m < 32; m <<= 1) {
            sm += __shfl_xor(sm, m, 64);
            sq += __shfl_xor(sq, m, 64);
        }
        float mu = sm * (1.0f / 128.0f);
        float var = sq * (1.0f / 128.0f) - mu * mu;
        float rs = rsqrtf(var + 1e-5f);
        float n0 = (v.x - mu) * rs * g4.x + b4.x;
        float n1 = (v.y - mu) * rs * g4.y + b4.y;
        float n2 = (v.z - mu) * rs * g4.z + b4.z;
        float n3 = (v.w - mu) * rs * g4.w + b4.w;
        unsigned lo = (unsigned)f2bf(n0) | ((unsigned)f2bf(n1) << 16);
        unsigned hi = (unsigned)f2bf(n2) | ((unsigned)f2bf(n3) << 16);
        unsigned long long dvv = (unsigned long long)lo | ((unsigned long long)hi << 32);
        int row = s * 8 + rsub;
        *(unsigned long long*)(pXY + swz(row, colq >> 3) + (colq & 7) * 2) = dvv;
    }

    bar_lds();   // bar1: xn + w1t ready

    const f32x4 zero4 = {0.f, 0.f, 0.f, 0.f};
    const short8 zfrag = {0, 0, 0, 0, 0, 0, 0, 0};

    // xn fragments (lane col = token within wave tile, k = c)
    short8 afr[4];
    #pragma unroll
    for (int ks = 0; ks < 4; ++ks)
        afr[ks] = *(const short8*)(pXY + swz(arow, ks * 4 + ak));

    //---------------- gating (swapped): D[e][token] ----------------
    f32x4 accg = zero4;
    #pragma unroll
    for (int ks = 0; ks < 4; ++ks)
        accg = __builtin_amdgcn_mfma_f32_16x16x32_bf16(gfr[ks], afr[ks], accg, 0, 0, 0);

    const size_t trow = (size_t)(tok0 + arow);
    {
        // lane holds logits for token trow, experts e = ak*4 + r (valid ak<2)
        float lg0 = accg[0] + gb4.x;
        float lg1 = accg[1] + gb4.y;
        float lg2 = accg[2] + gb4.z;
        float lg3 = accg[3] + gb4.w;
        if (ak < 2) {
            f32x4 lgv = {lg0, lg1, lg2, lg3};
            *(f32x4*)(out + O1_OFF + trow * 8 + ak * 4) = lgv;
        }
        float mx = fmaxf(fmaxf(lg0, lg1), fmaxf(lg2, lg3));
        mx = fmaxf(mx, __shfl_xor(mx, 16, 64));
        float ex0 = __expf(lg0 - mx), ex1 = __expf(lg1 - mx);
        float ex2 = __expf(lg2 - mx), ex3 = __expf(lg3 - mx);
        float sm = ex0 + ex1 + ex2 + ex3;
        sm += __shfl_xor(sm, 16, 64);
        float inv = 1.0f / sm;
        if (ak < 2) {
            f32x4 pv = {ex0 * inv, ex1 * inv, ex2 * inv, ex3 * inv};
            *(f32x4*)(pRW + arow * 8 + ak * 4) = pv;
        }
    }

    //---------------- stage B (swapped): y^T per token in-lane ----------------
    f32x4 accb[8];
    #pragma unroll
    for (int nt = 0; nt < 8; ++nt) accb[nt] = zero4;
    #pragma unroll
    for (int ks = 0; ks < 4; ++ks)
        #pragma unroll
        for (int nt = 0; nt < 8; ++nt) {
            short8 wfr = *(const short8*)(pW + swz(nt * 16 + col, ks * 4 + ak));
            accb[nt] = __builtin_amdgcn_mfma_f32_16x16x32_bf16(wfr, afr[ks], accb[nt], 0, 0, 0);
        }

    // exact-erf GELU; lane holds token arow, ei = nt*16 + ak*4 + r -> 8B packed write
    #pragma unroll
    for (int nt = 0; nt < 8; ++nt) {
        float y0 = accb[nt][0], y1 = accb[nt][1], y2 = accb[nt][2], y3 = accb[nt][3];
        y0 = 0.5f * y0 * (1.0f + erff(y0 * 0.70710678118654752f));
        y1 = 0.5f * y1 * (1.0f + erff(y1 * 0.70710678118654752f));
        y2 = 0.5f * y2 * (1.0f + erff(y2 * 0.70710678118654752f));
        y3 = 0.5f * y3 * (1.0f + erff(y3 * 0.70710678118654752f));
        unsigned lo = (unsigned)f2bf(y0) | ((unsigned)f2bf(y1) << 16);
        unsigned hi = (unsigned)f2bf(y2) | ((unsigned)f2bf(y3) << 16);
        unsigned long long dv = (unsigned long long)lo | ((unsigned long long)hi << 32);
        *(unsigned long long*)(pXY + swz(arow, nt * 2 + (ak >> 1)) + (ak & 1) * 8) = dv;
    }

    bar_lds();   // bar2: all stage-B w1t reads done -> w1t region reusable

    // staged w2 -> w2t[(e,c)][i] bf16, chunk' = (rc*2+half) ^ ((c>>2)&3)
    #pragma unroll
    for (int cc = 0; cc < 4; ++cc) {
        int c = colq + cc;
        int rc = e2 * 128 + c;
        int a = (c >> 2) & 3;
        *(uint4*)(pW + (((rc * 2 + 0) ^ a) << 4)) =
            make_uint4(pk[cc][0], pk[cc][1], pk[cc][2], pk[cc][3]);
        *(uint4*)(pW + (((rc * 2 + 1) ^ a) << 4)) =
            make_uint4(pk[cc][4], pk[cc][5], pk[cc][6], pk[cc][7]);
    }

    bar_lds();   // bar3: w2t + y + pRW ready

    //---------------- P4: per-expert GEMM -> LDS transpose -> full-line stores ---
    f32x4 agg[8];
    #pragma unroll
    for (int nt = 0; nt < 8; ++nt) agg[nt] = zero4;

    #pragma unroll
    for (int e = 0; e < 8; ++e) {
        float rwe[4];
        #pragma unroll
        for (int r = 0; r < 4; ++r)
            rwe[r] = pRW[(rb + ak * 4 + r) * 8 + e];
        short8 alo = *(const short8*)(pXY + swz(arow, 2 * e + (ak & 1)));
        short8 af = (ak < 2) ? alo : zfrag;    // K=16 padded to 32
        f32x4 ot[8];
        #pragma unroll
        for (int nt = 0; nt < 8; ++nt) {
            int c = nt * 16 + col;
            int rc = e * 128 + c;
            int a = (c >> 2) & 3;
            short8 blo = *(const short8*)(pW + (((rc * 2 + (ak & 1)) ^ a) << 4));
            short8 bf = (ak < 2) ? blo : zfrag;
            ot[nt] = __builtin_amdgcn_mfma_f32_16x16x32_bf16(af, bf, zero4, 0, 0, 0);
            #pragma unroll
            for (int r = 0; r < 4; ++r)
                agg[nt][r] += rwe[r] * ot[nt][r];
        }
        // MFMA-layout -> bf16 transpose slice (wave-private rows)
        #pragma unroll
        for (int nt = 0; nt < 8; ++nt)
            #pragma unroll
            for (int r = 0; r < 4; ++r)
                *(unsigned short*)(pTR + tswz(rb + ak * 4 + r, nt * 16 + col)) = f2bf(ot[nt][r]);
        fence_lds();   // drain DS writes + block compiler reordering (TBAA)
        // read back row-major: 2 full token-expert rows per instruction
        #pragma unroll
        for (int i2 = 0; i2 < 8; ++i2) {
            int row = rb + i2 * 2 + (l >> 5);
            int c0 = (l & 31) * 4;
            unsigned long long raw = *(const unsigned long long*)(pTR + tswz(row, c0));
            unsigned lo = (unsigned)raw, hi = (unsigned)(raw >> 32);
            f32x4 v;
            v[0] = __builtin_bit_cast(float, lo << 16);
            v[1] = __builtin_bit_cast(float, lo & 0xffff0000u);
            v[2] = __builtin_bit_cast(float, hi << 16);
            v[3] = __builtin_bit_cast(float, hi & 0xffff0000u);
            *(f32x4*)(out + O2_OFF + (size_t)(tok0 + row) * 1024 + e * 128 + c0) = v;
        }
        asm volatile("" ::: "memory");   // keep next expert's writes after these reads
    }

    bar_lds();   // bar4: all waves' w2t reads done -> pW reusable for agg (f32)

    //---------------- epilogue: f32 agg through pW (R0-verified scheme) ----------
    #pragma unroll
    for (int nt = 0; nt < 8; ++nt) {
        int c = nt * 16 + col;
        #pragma unroll
        for (int r = 0; r < 4; ++r) {
            int row = rb + ak * 4 + r;
            *(float*)(pW + row * 512 + ((c << 2) ^ ((row & 4) << 2))) = agg[nt][r];
        }
    }

    bar_lds();   // bar5: agg tile ready in P0 layout

    #pragma unroll
    for (int s = 0; s < 8; ++s) {
        int row = s * 8 + rsub;
        f32x4 a4 = *(const f32x4*)(pW + row * 512 + ((colq << 2) ^ ((row & 4) << 2)));
        float4 o;
        o.x = xv[s].x + a4[0];
        o.y = xv[s].y + a4[1];
        o.z = xv[s].z + a4[2];
        o.w = xv[s].w + a4[3];
        *(float4*)(out + (size_t)(tok0 + row) * 128 + colq) = o;
    }
}

extern "C" void kernel_launch(void* const* d_in, const int* in_sizes, int n_in,
                              void* d_out, int out_size, void* d_ws, size_t ws_size,
                              hipStream_t stream) {
    const float* x      = (const float*)d_in[0];
    const float* ln_g   = (const float*)d_in[1];
    const float* ln_b   = (const float*)d_in[2];
    const float* gate_w = (const float*)d_in[3];
    const float* gate_b = (const float*)d_in[4];
    const float* w1     = (const float*)d_in[5];
    const float* w2     = (const float*)d_in[6];
    float* out = (float*)d_out;
    (void)in_sizes; (void)n_in; (void)out_size; (void)d_ws; (void)ws_size;
    moe_fused<<<dim3(1024), dim3(256), 0, stream>>>(x, ln_g, ln_b, gate_w, gate_b, w1, w2, out);
}